// Round 7
// baseline (207.764 us; speedup 1.0000x reference)
//
#include <hip/hip_runtime.h>
#include <hip/hip_fp16.h>
#include <cstdint>

typedef unsigned short u16;
typedef __attribute__((ext_vector_type(8))) short short8;
typedef __attribute__((ext_vector_type(4))) float float4v;

#define NTOK 8192
#define HDIM 1024
#define NEXP 8
#define TM 128
#define TN 128
#define BK 64
#define MAXT 136   // max m-tiles over all experts: 16384/128 + 8 rounding partials
#define WBLK 8192  // prep: W-transpose blocks (32 x 32 x 8)
#define RBLK 2048  // prep: router blocks (4 tokens each)
#define ABUF (TM * BK)   // one A/B buffer in u16 elems (16 KB)

__device__ __forceinline__ u16 f2bf(float f) {
    union { float f; uint32_t u; } v; v.f = f;
    uint32_t u = v.u;
    return (u16)((u + 0x7FFFu + ((u >> 16) & 1u)) >> 16);
}

// async global->LDS, 16B per lane; LDS dest = wave-uniform base + lane*16
__device__ __forceinline__ void gll16(const u16* g, u16* l) {
    __builtin_amdgcn_global_load_lds(
        (const __attribute__((address_space(1))) uint32_t*)g,
        (__attribute__((address_space(3))) uint32_t*)l,
        16, 0, 0);
}

// ---------------- fused prep: W transpose+quantize AND router AND ctrl zeroing ---------
__global__ __launch_bounds__(256) void prep(const float* __restrict__ x,
                                            const float* __restrict__ rw,
                                            const float* __restrict__ ew,
                                            u16* __restrict__ x_bf,
                                            u16* __restrict__ w_bf,
                                            float* __restrict__ wt0,
                                            float* __restrict__ wt1,
                                            float* __restrict__ biasv,
                                            int* __restrict__ sel,
                                            int* __restrict__ ctrl) {
    if (blockIdx.x == 0 && threadIdx.x < 132) ctrl[threadIdx.x] = 0;  // counts[8x16] + done

    if (blockIdx.x < WBLK) {
        __shared__ float tile[32][33];
        const int bid = blockIdx.x;
        const int e  = bid >> 10;
        const int k0 = (bid & 31) * 32;
        const int n0 = ((bid >> 5) & 31) * 32;
        const int r = threadIdx.x >> 3;        // 0..31
        const int c = (threadIdx.x & 7) * 4;   // 0,4,...,28
        const float4 v = *(const float4*)(ew + ((size_t)e << 20) + (size_t)(k0 + r) * HDIM + n0 + c);
        tile[r][c] = v.x; tile[r][c+1] = v.y; tile[r][c+2] = v.z; tile[r][c+3] = v.w;
        __syncthreads();
        ushort4 o;
        o.x = f2bf(tile[c][r]); o.y = f2bf(tile[c+1][r]);
        o.z = f2bf(tile[c+2][r]); o.w = f2bf(tile[c+3][r]);
        *(ushort4*)(w_bf + ((size_t)e << 20) + (size_t)(n0 + r) * HDIM + k0 + c) = o;
    } else {
        const int wv = threadIdx.x >> 6;
        const int l  = threadIdx.x & 63;
        const int n  = (blockIdx.x - WBLK) * 4 + wv;  // one wave per token
        const float4* xr = (const float4*)(x + (size_t)n * HDIM);
        ushort4* xo = (ushort4*)(x_bf + (size_t)n * HDIM);

        float4 xv[4];
#pragma unroll
        for (int t = 0; t < 4; t++) {
            xv[t] = xr[t * 64 + l];
            ushort4 p;
            p.x = f2bf(xv[t].x); p.y = f2bf(xv[t].y);
            p.z = f2bf(xv[t].z); p.w = f2bf(xv[t].w);
            xo[t * 64 + l] = p;
        }

        float logits[NEXP];
#pragma unroll
        for (int e = 0; e < NEXP; e++) {
            const float4* rwe = (const float4*)(rw + e * HDIM);
            float acc = 0.f;
#pragma unroll
            for (int t = 0; t < 4; t++) {
                const float4 r = rwe[t * 64 + l];
                acc += xv[t].x * r.x + xv[t].y * r.y + xv[t].z * r.z + xv[t].w * r.w;
            }
#pragma unroll
            for (int s = 32; s > 0; s >>= 1) acc += __shfl_xor(acc, s, 64);
            logits[e] = acc;
        }

        if (l == 0) {
            float mx = logits[0];
#pragma unroll
            for (int e = 1; e < NEXP; e++) mx = fmaxf(mx, logits[e]);
            float p[NEXP]; float sum = 0.f;
#pragma unroll
            for (int e = 0; e < NEXP; e++) { p[e] = expf(logits[e] - mx); sum += p[e]; }
            const float inv = 1.f / sum;
#pragma unroll
            for (int e = 0; e < NEXP; e++) p[e] *= inv;
            int e0 = 0;
#pragma unroll
            for (int e = 1; e < NEXP; e++) if (p[e] > p[e0]) e0 = e;  // ties -> lowest idx
            int e1 = (e0 == 0) ? 1 : 0;
#pragma unroll
            for (int e = 0; e < NEXP; e++) if (e != e0 && p[e] > p[e1]) e1 = e;
            const float p0 = p[e0], p1 = p[e1];
            const float wsum = p0 + p1 + 1e-6f;
            const float w0 = p0 / wsum, w1 = p1 / wsum;
            wt0[n] = w0; wt1[n] = w1;
            biasv[n] = w0 * p0 + w1 * p1;
            sel[n] = e0 | (e1 << 8);
        }
    }
}

// ---------------- list build + fused tile planning (last block plans) ------------------
__global__ __launch_bounds__(256) void build_lists(const int* __restrict__ sel,
                                                   int* __restrict__ lists,
                                                   int* __restrict__ ctrl,
                                                   int* __restrict__ tmap) {
    const int n  = blockIdx.x * 256 + threadIdx.x;
    const int wv = threadIdx.x >> 6;
    const int l  = threadIdx.x & 63;
    const int s  = sel[n];
    const int e0 = s & 0xFF, e1 = s >> 8;
    __shared__ int wcnt[NEXP][4];
    __shared__ int ebase[NEXP];
    int pf0 = 0, pf1 = 0;
    const unsigned long long ltmask = (1ULL << l) - 1ULL;
#pragma unroll
    for (int e = 0; e < NEXP; e++) {
        const int slot = (e0 == e) ? 0 : ((e1 == e) ? 1 : -1);
        const unsigned long long bal = __ballot(slot >= 0);
        const int pf = __popcll(bal & ltmask);
        if (slot == 0) pf0 = pf;
        if (slot == 1) pf1 = pf;
        if (l == 0) wcnt[e][wv] = __popcll(bal);
    }
    __syncthreads();
    if (threadIdx.x < NEXP) {
        const int e = threadIdx.x;
        const int tot = wcnt[e][0] + wcnt[e][1] + wcnt[e][2] + wcnt[e][3];
        ebase[e] = atomicAdd(&ctrl[e * 16], tot);   // counters 64B apart
    }
    __syncthreads();
    int off0 = ebase[e0], off1 = ebase[e1];
#pragma unroll
    for (int i = 0; i < 4; i++) {
        off0 += (i < wv) ? wcnt[e0][i] : 0;
        off1 += (i < wv) ? wcnt[e1][i] : 0;
    }
    lists[e0 * NTOK + off0 + pf0] = n;              // slot 0
    lists[e1 * NTOK + off1 + pf1] = n | 0x10000;    // slot 1

    // ---- last block to finish plans the dense tile map ----
    __shared__ int lastflag;
    __threadfence();
    if (threadIdx.x == 0) lastflag = (atomicAdd(&ctrl[128], 1) == (int)gridDim.x - 1);
    __syncthreads();
    if (lastflag) {
        __shared__ int tbase[NEXP + 1];
        if (threadIdx.x == 0) {
            int acc = 0;
            for (int e = 0; e < NEXP; e++) {
                tbase[e] = acc;
                acc += (atomicAdd(&ctrl[e * 16], 0) + TM - 1) / TM;  // device-scope read
            }
            tbase[NEXP] = acc;
        }
        __syncthreads();
        for (int i = threadIdx.x; i < MAXT; i += 256) {
            int v = -1;
#pragma unroll
            for (int e = 0; e < NEXP; e++)
                if (i >= tbase[e] && i < tbase[e + 1]) v = (e << 16) | (i - tbase[e]);
            tmap[i] = v;
        }
    }
}

// ---------------- grouped GEMM: 128x128, BK=64, DOUBLE-BUFFERED LDS (1 barrier/iter) ---
__global__ __launch_bounds__(256) void moe_gemm(const u16* __restrict__ x_bf,
                                                const u16* __restrict__ wt_bf,
                                                const int* __restrict__ lists,
                                                const int* __restrict__ ctrl,
                                                const int* __restrict__ tmap,
                                                const float* __restrict__ wt0,
                                                const float* __restrict__ wt1,
                                                const float* __restrict__ biasv,
                                                __half* __restrict__ stage0,
                                                __half* __restrict__ stage1) {
    const int ent = tmap[blockIdx.x];
    if (ent < 0) return;
    const int e = ent >> 16;
    const int tile_m = (ent & 0xFFFF) * TM;
    const int cnt = ctrl[e * 16];
    const int tn = blockIdx.y * TN;

    __shared__ u16 lA[2 * ABUF];  // 2 x 16 KB, [row][64] with k-seg XOR swizzle
    __shared__ u16 lB[2 * ABUF];  // 2 x 16 KB
    __shared__ int   toks[TM];
    __shared__ float wgt[TM];
    __shared__ float bia[TM];
    __shared__ int   slt[TM];

    const int t  = threadIdx.x;
    const int wv = t >> 6;
    const int l  = t & 63;

    if (t < TM) {
        const int idx = tile_m + t;
        int tok = 0; float w = 0.f, b = 0.f; int sl = 0;
        if (idx < cnt) {
            const int entry = lists[e * NTOK + idx];
            tok = entry & 0xFFFF;
            sl = entry >> 16;
            w = sl ? wt1[tok] : wt0[tok];
            b = sl ? 0.f : biasv[tok];
        }
        toks[t] = tok; wgt[t] = w; bia[t] = b; slt[t] = sl;
    }
    __syncthreads();

    // staging: 16 chunks per matrix, chunk c = rows [8c,8c+8); wave handles chunks 4wv..4wv+3
    // lane l -> row 8c+(l>>3); global k-seg = (l&7)^(l>>3) (XOR swizzle), 16B per lane
    const int r_in = l >> 3;                 // 0..7
    const int koff = (((l & 7) ^ r_in)) * 8; // swizzled k offset (u16)
    const u16* pA[4]; const u16* pB[4]; int qoff[4];
#pragma unroll
    for (int i = 0; i < 4; i++) {
        const int c = wv * 4 + i;
        const int row = c * 8 + r_in;
        pA[i] = x_bf + (size_t)toks[row] * HDIM + koff;
        pB[i] = wt_bf + ((size_t)e << 20) + (size_t)(tn + row) * HDIM + koff;
        qoff[i] = c * 512;   // 1 KB chunk, wave-uniform base (within one buffer)
    }

    // compute: wave -> 64x64 subtile at (wm, wn)
    const int wm = (wv & 1) * 64;
    const int wn = (wv >> 1) * 64;
    const int fm = l & 15;
    const int fq = l >> 4;     // 0..3 (k-seg within half)
    int aoff[4], boff[4];
#pragma unroll
    for (int i = 0; i < 4; i++) {
        const int ra = wm + i * 16 + fm;
        const int rb = wn + i * 16 + fm;
        aoff[i] = ra * 64 + ((fq ^ (ra & 7)) * 8);
        boff[i] = rb * 64 + ((fq ^ (rb & 7)) * 8);
    }

    float4v acc[4][4];
#pragma unroll
    for (int i = 0; i < 4; i++)
#pragma unroll
        for (int j = 0; j < 4; j++) { float4v z = {0.f, 0.f, 0.f, 0.f}; acc[i][j] = z; }

    // prologue: load k-tile 0 into buffer 0
#pragma unroll
    for (int i = 0; i < 4; i++) {
        gll16(pA[i], lA + qoff[i]);
        gll16(pB[i], lB + qoff[i]);
    }
    int p = 0;
    __syncthreads();   // vmcnt(0) drain + barrier: buf0 ready

    for (int k0 = 0; k0 < HDIM; k0 += BK) {
        const int nk = k0 + BK;
        if (nk < HDIM) {
            // prefetch next tile into the other buffer; overlaps with MFMA below
            const int pb = (p ^ 1) * ABUF;
#pragma unroll
            for (int i = 0; i < 4; i++) {
                gll16(pA[i] + nk, lA + pb + qoff[i]);
                gll16(pB[i] + nk, lB + pb + qoff[i]);
            }
        }

        const int cb = p * ABUF;
#pragma unroll
        for (int kh = 0; kh < 2; kh++) {
            short8 af[4], bf[4];
#pragma unroll
            for (int mf = 0; mf < 4; mf++)
                af[mf] = *(const short8*)&lA[cb + (aoff[mf] ^ (kh << 5))];
#pragma unroll
            for (int nf = 0; nf < 4; nf++)
                bf[nf] = *(const short8*)&lB[cb + (boff[nf] ^ (kh << 5))];
#pragma unroll
            for (int mf = 0; mf < 4; mf++)
#pragma unroll
                for (int nf = 0; nf < 4; nf++)
                    acc[mf][nf] = __builtin_amdgcn_mfma_f32_16x16x32_bf16(af[mf], bf[nf], acc[mf][nf], 0, 0, 0);
        }

        if (nk < HDIM) {
            __syncthreads();   // drains prefetch vmcnt + guards buffer swap
            p ^= 1;
        }
    }

    // epilogue: stage[slot][tok][h] = fp16(acc*w + b)  -- plain stores, race-free
#pragma unroll
    for (int mf = 0; mf < 4; mf++) {
#pragma unroll
        for (int r = 0; r < 4; r++) {
            const int m_local = wm + mf * 16 + fq * 4 + r;
            if (tile_m + m_local < cnt) {
                const int tok = toks[m_local];
                const float w = wgt[m_local], b = bia[m_local];
                __half* sp = (slt[m_local] ? stage1 : stage0) + (size_t)tok * HDIM;
#pragma unroll
                for (int nf = 0; nf < 4; nf++) {
                    const int h = tn + wn + nf * 16 + fm;
                    sp[h] = __float2half(acc[mf][nf][r] * w + b);
                }
            }
        }
    }
}

// ---------------- combine: out = stage0 + stage1 (fully coalesced) ----------------
__global__ __launch_bounds__(256) void combine(const __half* __restrict__ s0,
                                               const __half* __restrict__ s1,
                                               float* __restrict__ out) {
    const size_t idx = ((size_t)blockIdx.x * 256 + threadIdx.x) * 8;
    union { uint4 v; __half h[8]; } a, b;
    a.v = *(const uint4*)(s0 + idx);
    b.v = *(const uint4*)(s1 + idx);
    float4 o0, o1;
    o0.x = __half2float(a.h[0]) + __half2float(b.h[0]);
    o0.y = __half2float(a.h[1]) + __half2float(b.h[1]);
    o0.z = __half2float(a.h[2]) + __half2float(b.h[2]);
    o0.w = __half2float(a.h[3]) + __half2float(b.h[3]);
    o1.x = __half2float(a.h[4]) + __half2float(b.h[4]);
    o1.y = __half2float(a.h[5]) + __half2float(b.h[5]);
    o1.z = __half2float(a.h[6]) + __half2float(b.h[6]);
    o1.w = __half2float(a.h[7]) + __half2float(b.h[7]);
    *(float4*)(out + idx)     = o0;
    *(float4*)(out + idx + 4) = o1;
}

extern "C" void kernel_launch(void* const* d_in, const int* in_sizes, int n_in,
                              void* d_out, int out_size, void* d_ws, size_t ws_size,
                              hipStream_t stream) {
    const float* x  = (const float*)d_in[0];   // [4,2048,1024]
    const float* rw = (const float*)d_in[1];   // [8,1024]
    const float* ew = (const float*)d_in[2];   // [8,1024,1024]
    float* out = (float*)d_out;

    char* ws = (char*)d_ws;
    u16*    x_bf   = (u16*)ws;                          // 16 MiB
    u16*    w_bf   = (u16*)(ws + 16777216);             // 16 MiB
    __half* stage0 = (__half*)(ws + 33554432);          // 16 MiB
    __half* stage1 = (__half*)(ws + 50331648);          // 16 MiB
    float*  wt0    = (float*)(ws + 67108864);           // 32 KiB
    float*  wt1    = (float*)(ws + 67141632);           // 32 KiB
    float*  biasv  = (float*)(ws + 67174400);           // 32 KiB
    int*    sel    = (int*)(ws + 67207168);             // 32 KiB
    int*    lists  = (int*)(ws + 67239936);             // 256 KiB
    int*    ctrl   = (int*)(ws + 67502080);             // 544 B: counts[8*16] + done
    int*    tmap   = (int*)(ws + 67502720);             // 544 B

    prep<<<WBLK + RBLK, 256, 0, stream>>>(x, rw, ew, x_bf, w_bf, wt0, wt1, biasv, sel, ctrl);
    build_lists<<<NTOK / 256, 256, 0, stream>>>(sel, lists, ctrl, tmap);
    moe_gemm<<<dim3(MAXT, HDIM / TN, 1), 256, 0, stream>>>(
        x_bf, w_bf, lists, ctrl, tmap, wt0, wt1, biasv, stage0, stage1);
    combine<<<(NTOK * HDIM) / (256 * 8), 256, 0, stream>>>(stage0, stage1, out);
}

// Round 8
// 198.790 us; speedup vs baseline: 1.0451x; 1.0451x over previous
//
#include <hip/hip_runtime.h>
#include <hip/hip_fp16.h>
#include <cstdint>

typedef unsigned short u16;
typedef __attribute__((ext_vector_type(8))) short short8;
typedef __attribute__((ext_vector_type(4))) float float4v;

#define NTOK 8192
#define HDIM 1024
#define NEXP 8
#define TM 128
#define TN 128
#define BK 32
#define NITER (HDIM / BK)        // 32
#define ABUF (TM * BK)           // one A or B buffer: 4096 u16 = 8 KB
#define MAXT 136   // max m-tiles over all experts: 16384/128 + 8 rounding partials
#define WBLK 8192  // prep: W-transpose blocks (32 x 32 x 8)
#define RBLK 2048  // prep: router blocks (4 tokens each)

__device__ __forceinline__ u16 f2bf(float f) {
    union { float f; uint32_t u; } v; v.f = f;
    uint32_t u = v.u;
    return (u16)((u + 0x7FFFu + ((u >> 16) & 1u)) >> 16);
}

// async global->LDS, 16B per lane; LDS dest = wave-uniform base + lane*16
__device__ __forceinline__ void gll16(const u16* g, u16* l) {
    __builtin_amdgcn_global_load_lds(
        (const __attribute__((address_space(1))) uint32_t*)g,
        (__attribute__((address_space(3))) uint32_t*)l,
        16, 0, 0);
}

// ---------------- fused prep: W transpose+quantize AND router AND ctrl zeroing ---------
__global__ __launch_bounds__(256) void prep(const float* __restrict__ x,
                                            const float* __restrict__ rw,
                                            const float* __restrict__ ew,
                                            u16* __restrict__ x_bf,
                                            u16* __restrict__ w_bf,
                                            float* __restrict__ wt0,
                                            float* __restrict__ wt1,
                                            float* __restrict__ biasv,
                                            int* __restrict__ sel,
                                            int* __restrict__ ctrl) {
    if (blockIdx.x == 0 && threadIdx.x < 132) ctrl[threadIdx.x] = 0;  // counts[8x16] + done

    if (blockIdx.x < WBLK) {
        __shared__ float tile[32][33];
        const int bid = blockIdx.x;
        const int e  = bid >> 10;
        const int k0 = (bid & 31) * 32;
        const int n0 = ((bid >> 5) & 31) * 32;
        const int r = threadIdx.x >> 3;        // 0..31
        const int c = (threadIdx.x & 7) * 4;   // 0,4,...,28
        const float4 v = *(const float4*)(ew + ((size_t)e << 20) + (size_t)(k0 + r) * HDIM + n0 + c);
        tile[r][c] = v.x; tile[r][c+1] = v.y; tile[r][c+2] = v.z; tile[r][c+3] = v.w;
        __syncthreads();
        ushort4 o;
        o.x = f2bf(tile[c][r]); o.y = f2bf(tile[c+1][r]);
        o.z = f2bf(tile[c+2][r]); o.w = f2bf(tile[c+3][r]);
        *(ushort4*)(w_bf + ((size_t)e << 20) + (size_t)(n0 + r) * HDIM + k0 + c) = o;
    } else {
        const int wv = threadIdx.x >> 6;
        const int l  = threadIdx.x & 63;
        const int n  = (blockIdx.x - WBLK) * 4 + wv;  // one wave per token
        const float4* xr = (const float4*)(x + (size_t)n * HDIM);
        ushort4* xo = (ushort4*)(x_bf + (size_t)n * HDIM);

        float4 xv[4];
#pragma unroll
        for (int t = 0; t < 4; t++) {
            xv[t] = xr[t * 64 + l];
            ushort4 p;
            p.x = f2bf(xv[t].x); p.y = f2bf(xv[t].y);
            p.z = f2bf(xv[t].z); p.w = f2bf(xv[t].w);
            xo[t * 64 + l] = p;
        }

        float logits[NEXP];
#pragma unroll
        for (int e = 0; e < NEXP; e++) {
            const float4* rwe = (const float4*)(rw + e * HDIM);
            float acc = 0.f;
#pragma unroll
            for (int t = 0; t < 4; t++) {
                const float4 r = rwe[t * 64 + l];
                acc += xv[t].x * r.x + xv[t].y * r.y + xv[t].z * r.z + xv[t].w * r.w;
            }
#pragma unroll
            for (int s = 32; s > 0; s >>= 1) acc += __shfl_xor(acc, s, 64);
            logits[e] = acc;
        }

        if (l == 0) {
            float mx = logits[0];
#pragma unroll
            for (int e = 1; e < NEXP; e++) mx = fmaxf(mx, logits[e]);
            float p[NEXP]; float sum = 0.f;
#pragma unroll
            for (int e = 0; e < NEXP; e++) { p[e] = expf(logits[e] - mx); sum += p[e]; }
            const float inv = 1.f / sum;
#pragma unroll
            for (int e = 0; e < NEXP; e++) p[e] *= inv;
            int e0 = 0;
#pragma unroll
            for (int e = 1; e < NEXP; e++) if (p[e] > p[e0]) e0 = e;  // ties -> lowest idx
            int e1 = (e0 == 0) ? 1 : 0;
#pragma unroll
            for (int e = 0; e < NEXP; e++) if (e != e0 && p[e] > p[e1]) e1 = e;
            const float p0 = p[e0], p1 = p[e1];
            const float wsum = p0 + p1 + 1e-6f;
            const float w0 = p0 / wsum, w1 = p1 / wsum;
            wt0[n] = w0; wt1[n] = w1;
            biasv[n] = w0 * p0 + w1 * p1;
            sel[n] = e0 | (e1 << 8);
        }
    }
}

// ---------------- list build + fused tile planning (last block plans) ------------------
__global__ __launch_bounds__(256) void build_lists(const int* __restrict__ sel,
                                                   int* __restrict__ lists,
                                                   int* __restrict__ ctrl,
                                                   int* __restrict__ tmap) {
    const int n  = blockIdx.x * 256 + threadIdx.x;
    const int wv = threadIdx.x >> 6;
    const int l  = threadIdx.x & 63;
    const int s  = sel[n];
    const int e0 = s & 0xFF, e1 = s >> 8;
    __shared__ int wcnt[NEXP][4];
    __shared__ int ebase[NEXP];
    int pf0 = 0, pf1 = 0;
    const unsigned long long ltmask = (1ULL << l) - 1ULL;
#pragma unroll
    for (int e = 0; e < NEXP; e++) {
        const int slot = (e0 == e) ? 0 : ((e1 == e) ? 1 : -1);
        const unsigned long long bal = __ballot(slot >= 0);
        const int pf = __popcll(bal & ltmask);
        if (slot == 0) pf0 = pf;
        if (slot == 1) pf1 = pf;
        if (l == 0) wcnt[e][wv] = __popcll(bal);
    }
    __syncthreads();
    if (threadIdx.x < NEXP) {
        const int e = threadIdx.x;
        const int tot = wcnt[e][0] + wcnt[e][1] + wcnt[e][2] + wcnt[e][3];
        ebase[e] = atomicAdd(&ctrl[e * 16], tot);   // counters 64B apart
    }
    __syncthreads();
    int off0 = ebase[e0], off1 = ebase[e1];
#pragma unroll
    for (int i = 0; i < 4; i++) {
        off0 += (i < wv) ? wcnt[e0][i] : 0;
        off1 += (i < wv) ? wcnt[e1][i] : 0;
    }
    lists[e0 * NTOK + off0 + pf0] = n;              // slot 0
    lists[e1 * NTOK + off1 + pf1] = n | 0x10000;    // slot 1

    // ---- last block to finish plans the dense tile map ----
    __shared__ int lastflag;
    __threadfence();
    if (threadIdx.x == 0) lastflag = (atomicAdd(&ctrl[128], 1) == (int)gridDim.x - 1);
    __syncthreads();
    if (lastflag) {
        __shared__ int tbase[NEXP + 1];
        if (threadIdx.x == 0) {
            int acc = 0;
            for (int e = 0; e < NEXP; e++) {
                tbase[e] = acc;
                acc += (atomicAdd(&ctrl[e * 16], 0) + TM - 1) / TM;  // device-scope read
            }
            tbase[NEXP] = acc;
        }
        __syncthreads();
        for (int i = threadIdx.x; i < MAXT; i += 256) {
            int v = -1;
#pragma unroll
            for (int e = 0; e < NEXP; e++)
                if (i >= tbase[e] && i < tbase[e + 1]) v = (e << 16) | (i - tbase[e]);
            tmap[i] = v;
        }
    }
}

// ---------------- grouped GEMM: 128x128, BK=32, 3-buffer vmcnt-pipelined K-loop --------
// Barrier = `s_waitcnt vmcnt(4); s_barrier` -- leaves the 4 just-issued prefetches in
// flight (waits only the 4 older loads = this iter's tile). 3 buffers make the
// overwrite hazard safe: buf (i+1)%3 was last read at iter i-2, sealed by barrier i-1.
__global__ __launch_bounds__(256) void moe_gemm(const u16* __restrict__ x_bf,
                                                const u16* __restrict__ wt_bf,
                                                const int* __restrict__ lists,
                                                const int* __restrict__ ctrl,
                                                const int* __restrict__ tmap,
                                                const float* __restrict__ wt0,
                                                const float* __restrict__ wt1,
                                                const float* __restrict__ biasv,
                                                __half* __restrict__ stage0,
                                                __half* __restrict__ stage1) {
    const int ent = tmap[blockIdx.x];
    if (ent < 0) return;
    const int e = ent >> 16;
    const int tile_m = (ent & 0xFFFF) * TM;
    const int cnt = ctrl[e * 16];
    const int tn = blockIdx.y * TN;

    __shared__ u16 lA[3 * ABUF];  // 3 x 8 KB
    __shared__ u16 lB[3 * ABUF];  // 3 x 8 KB
    __shared__ int   toks[TM];
    __shared__ float wgt[TM];
    __shared__ float bia[TM];
    __shared__ int   slt[TM];

    const int t  = threadIdx.x;
    const int wv = t >> 6;
    const int l  = t & 63;

    if (t < TM) {
        const int idx = tile_m + t;
        int tok = 0; float w = 0.f, b = 0.f; int sl = 0;
        if (idx < cnt) {
            const int entry = lists[e * NTOK + idx];
            tok = entry & 0xFFFF;
            sl = entry >> 16;
            w = sl ? wt1[tok] : wt0[tok];
            b = sl ? 0.f : biasv[tok];
        }
        toks[t] = tok; wgt[t] = w; bia[t] = b; slt[t] = sl;
    }
    __syncthreads();

    // staging: 8 chunks per matrix per k-tile; chunk c = rows [16c,16c+16), 1 KB.
    // wave wv handles chunks {2wv, 2wv+1} of A and B.
    // lane l -> row 16c+(l>>2), global k-seg = (l&3)^((l>>2)&3) (XOR swizzle), 16B/lane
    const int r_in = l >> 2;                       // 0..15
    const int koff = ((l & 3) ^ (r_in & 3)) * 8;   // swizzled k offset (u16)
    const u16* pA[2]; const u16* pB[2]; int qoff[2];
#pragma unroll
    for (int i = 0; i < 2; i++) {
        const int c = wv * 2 + i;
        const int row = c * 16 + r_in;
        pA[i] = x_bf + (size_t)toks[row] * HDIM + koff;
        pB[i] = wt_bf + ((size_t)e << 20) + (size_t)(tn + row) * HDIM + koff;
        qoff[i] = c * 512;   // 1 KB chunk, wave-uniform base (within one buffer)
    }

    // compute: wave -> 64x64 subtile at (wm, wn)
    const int wm = (wv & 1) * 64;
    const int wn = (wv >> 1) * 64;
    const int fm = l & 15;
    const int fq = l >> 4;     // 0..3 (k-seg)
    int aoff[4], boff[4];
#pragma unroll
    for (int i = 0; i < 4; i++) {
        const int ra = wm + i * 16 + fm;
        const int rb = wn + i * 16 + fm;
        aoff[i] = ra * 32 + ((fq ^ (ra & 3)) * 8);
        boff[i] = rb * 32 + ((fq ^ (rb & 3)) * 8);
    }

    float4v acc[4][4];
#pragma unroll
    for (int i = 0; i < 4; i++)
#pragma unroll
        for (int j = 0; j < 4; j++) { float4v z = {0.f, 0.f, 0.f, 0.f}; acc[i][j] = z; }

    // prologue: issue k-tile 0 into buffer 0 (waited by iter-0's vmcnt(4))
    gll16(pA[0], lA + qoff[0]);
    gll16(pA[1], lA + qoff[1]);
    gll16(pB[0], lB + qoff[0]);
    gll16(pB[1], lB + qoff[1]);

    int cur = 0, nxt = 1;
    for (int it = 0; it < NITER; ++it) {
        if (it < NITER - 1) {
            const int nk = (it + 1) * BK;
            u16* la = lA + nxt * ABUF;
            u16* lb = lB + nxt * ABUF;
            gll16(pA[0] + nk, la + qoff[0]);
            gll16(pA[1] + nk, la + qoff[1]);
            gll16(pB[0] + nk, lb + qoff[0]);
            gll16(pB[1] + nk, lb + qoff[1]);
            // wait the 4 OLDER loads (this iter's tile), leave the 4 prefetches in flight
            asm volatile("s_waitcnt vmcnt(4)\n\ts_barrier" ::: "memory");
        } else {
            asm volatile("s_waitcnt vmcnt(0)\n\ts_barrier" ::: "memory");
        }

        const u16* ca = lA + cur * ABUF;
        const u16* cb = lB + cur * ABUF;
        short8 af[4], bf[4];
#pragma unroll
        for (int mf = 0; mf < 4; mf++) af[mf] = *(const short8*)&ca[aoff[mf]];
#pragma unroll
        for (int nf = 0; nf < 4; nf++) bf[nf] = *(const short8*)&cb[boff[nf]];
#pragma unroll
        for (int mf = 0; mf < 4; mf++)
#pragma unroll
            for (int nf = 0; nf < 4; nf++)
                acc[mf][nf] = __builtin_amdgcn_mfma_f32_16x16x32_bf16(af[mf], bf[nf], acc[mf][nf], 0, 0, 0);

        cur = nxt;
        nxt = (nxt == 2) ? 0 : nxt + 1;
    }

    // epilogue: stage[slot][tok][h] = fp16(acc*w + b)  -- plain stores, race-free
#pragma unroll
    for (int mf = 0; mf < 4; mf++) {
#pragma unroll
        for (int r = 0; r < 4; r++) {
            const int m_local = wm + mf * 16 + fq * 4 + r;
            if (tile_m + m_local < cnt) {
                const int tok = toks[m_local];
                const float w = wgt[m_local], b = bia[m_local];
                __half* sp = (slt[m_local] ? stage1 : stage0) + (size_t)tok * HDIM;
#pragma unroll
                for (int nf = 0; nf < 4; nf++) {
                    const int h = tn + wn + nf * 16 + fm;
                    sp[h] = __float2half(acc[mf][nf][r] * w + b);
                }
            }
        }
    }
}

// ---------------- combine: out = stage0 + stage1 (fully coalesced) ----------------
__global__ __launch_bounds__(256) void combine(const __half* __restrict__ s0,
                                               const __half* __restrict__ s1,
                                               float* __restrict__ out) {
    const size_t idx = ((size_t)blockIdx.x * 256 + threadIdx.x) * 8;
    union { uint4 v; __half h[8]; } a, b;
    a.v = *(const uint4*)(s0 + idx);
    b.v = *(const uint4*)(s1 + idx);
    float4 o0, o1;
    o0.x = __half2float(a.h[0]) + __half2float(b.h[0]);
    o0.y = __half2float(a.h[1]) + __half2float(b.h[1]);
    o0.z = __half2float(a.h[2]) + __half2float(b.h[2]);
    o0.w = __half2float(a.h[3]) + __half2float(b.h[3]);
    o1.x = __half2float(a.h[4]) + __half2float(b.h[4]);
    o1.y = __half2float(a.h[5]) + __half2float(b.h[5]);
    o1.z = __half2float(a.h[6]) + __half2float(b.h[6]);
    o1.w = __half2float(a.h[7]) + __half2float(b.h[7]);
    *(float4*)(out + idx)     = o0;
    *(float4*)(out + idx + 4) = o1;
}

extern "C" void kernel_launch(void* const* d_in, const int* in_sizes, int n_in,
                              void* d_out, int out_size, void* d_ws, size_t ws_size,
                              hipStream_t stream) {
    const float* x  = (const float*)d_in[0];   // [4,2048,1024]
    const float* rw = (const float*)d_in[1];   // [8,1024]
    const float* ew = (const float*)d_in[2];   // [8,1024,1024]
    float* out = (float*)d_out;

    char* ws = (char*)d_ws;
    u16*    x_bf   = (u16*)ws;                          // 16 MiB
    u16*    w_bf   = (u16*)(ws + 16777216);             // 16 MiB
    __half* stage0 = (__half*)(ws + 33554432);          // 16 MiB
    __half* stage1 = (__half*)(ws + 50331648);          // 16 MiB
    float*  wt0    = (float*)(ws + 67108864);           // 32 KiB
    float*  wt1    = (float*)(ws + 67141632);           // 32 KiB
    float*  biasv  = (float*)(ws + 67174400);           // 32 KiB
    int*    sel    = (int*)(ws + 67207168);             // 32 KiB
    int*    lists  = (int*)(ws + 67239936);             // 256 KiB
    int*    ctrl   = (int*)(ws + 67502080);             // 544 B: counts[8*16] + done
    int*    tmap   = (int*)(ws + 67502720);             // 544 B

    prep<<<WBLK + RBLK, 256, 0, stream>>>(x, rw, ew, x_bf, w_bf, wt0, wt1, biasv, sel, ctrl);
    build_lists<<<NTOK / 256, 256, 0, stream>>>(sel, lists, ctrl, tmap);
    moe_gemm<<<dim3(MAXT, HDIM / TN, 1), 256, 0, stream>>>(
        x_bf, w_bf, lists, ctrl, tmap, wt0, wt1, biasv, stage0, stage1);
    combine<<<(NTOK * HDIM) / (256 * 8), 256, 0, stream>>>(stage0, stage1, out);
}